// Round 15
// baseline (270.301 us; speedup 1.0000x reference)
//
#include <hip/hip_runtime.h>
#include <hip/hip_bf16.h>
#include <math.h>

#define B_   4
#define S_   4096
#define D_   1024
#define M_   (B_*S_)        // 16384 rows
#define NCAT (4*D_)         // 4096 concat projection cols
#define KD   1024

#define NCHUNK 128          // scan chunks along S
#define CHLEN  (S_/NCHUNK)  // 32

typedef __bf16 bf16x8 __attribute__((ext_vector_type(8)));
typedef float  f32x4  __attribute__((ext_vector_type(4)));
typedef ushort ushort8v __attribute__((ext_vector_type(8)));

__device__ __forceinline__ ushort sbf(float f) {           // f32 -> bf16 (RNE, hw cvt)
  return __builtin_bit_cast(ushort, (__bf16)f);
}
__device__ __forceinline__ uint pk2bf(float lo, float hi) {
  return (uint)sbf(lo) | ((uint)sbf(hi) << 16);
}
__device__ __forceinline__ float bf2f(uint bits16) {
  union { uint u; float f; } v; v.u = bits16 << 16;
  return v.f;
}
__device__ __forceinline__ float frcp(float x) { return __builtin_amdgcn_rcpf(x); }

// global -> LDS direct (16B per lane). LDS dest linear: wave-uniform base + lane*16.
#define GLL(g, l) __builtin_amdgcn_global_load_lds( \
  (const __attribute__((address_space(1))) uint32_t*)(uintptr_t)(g), \
  (__attribute__((address_space(3))) uint32_t*)(uint32_t)(uintptr_t)(l), 16, 0, 0)

#define MFMA_(a, b, c) __builtin_amdgcn_mfma_f32_16x16x32_bf16(a, b, c, 0, 0, 0)

// ---------------- K0: all dtype conversions in one kernel ----------------
// region 0: x -> xbf (M_*D_/4 quads)
// region 1: interleaved Wcat (NCAT*D_/4 quads): row n -> proj p=(n>>4)&3,
//           channel e=(n>>6)*16+(n&15)
// region 2: W_out -> woutb (D_*D_/4 quads)
#define NQ_X  (M_*D_/4)
#define NQ_W  (NCAT*D_/4)
#define NQ_O  (D_*D_/4)
__global__ void k_prep(const float* __restrict__ x,
                       const float* __restrict__ wdel, const float* __restrict__ wsel,
                       const float* __restrict__ win,  const float* __restrict__ wgat,
                       const float* __restrict__ wout,
                       ushort* __restrict__ xbf, ushort* __restrict__ wcat,
                       ushort* __restrict__ woutb) {
  int i = blockIdx.x * blockDim.x + threadIdx.x;
  const float* src;
  ushort* dst;
  size_t so, eo;
  if (i < NQ_X) {
    src = x; dst = xbf; so = (size_t)i * 4; eo = so;
  } else if (i < NQ_X + NQ_W) {
    const int q = i - NQ_X;
    const int E = q * 4;
    const int n = E >> 10, col = E & 1023;
    const int p = (n >> 4) & 3;
    const int e = ((n >> 6) << 4) + (n & 15);
    src = (p == 0) ? wdel : (p == 1) ? wsel : (p == 2) ? win : wgat;
    dst = wcat; so = (size_t)e * 1024 + col; eo = E;
  } else if (i < NQ_X + NQ_W + NQ_O) {
    const int q = i - NQ_X - NQ_W;
    src = wout; dst = woutb; so = (size_t)q * 4; eo = so;
  } else return;
  const float4 v = *(const float4*)&src[so];
  uint2 o;
  o.x = pk2bf(v.x, v.y);
  o.y = pk2bf(v.z, v.w);
  *(uint2*)&dst[eo] = o;
}

// -------- 256x256 GEMM, K-tile 64, ONE barrier/phase, ds_read prefetched 1 phase ----
// (R9/R14 structure verbatim -- best passing variant.)  C[m][n] = sum_k A[m][k]*B[n][k].
//   buf PB in {0, 32768} ushorts; A region at PB+0, B at PB+16384;
//   idx = kk*8192 + R*4096 + lr*32 + s*8; swizzle s = c ^ ((r>>1)&3) (0-conflict).
// MODE 0 fuses: activation epilogue (fast math), scanA chunk summaries (shfl compose),
// and a_base = sigmoid(log_a) inline.
template<int MODE>
__global__ __launch_bounds__(512, 2) void gemm10(
    const ushort* __restrict__ Ab, const ushort* __restrict__ Bb, int nbn,
    float* __restrict__ outf,
    ushort* __restrict__ dec, ushort* __restrict__ uu, ushort* __restrict__ gat,
    const float* __restrict__ log_a,
    float* __restrict__ cP, float* __restrict__ cL)
{
  __shared__ ushort lds[65536];  // 128 KB: 2 bufs x (A 32KB + B 32KB)

  const int nwg = gridDim.x;
  const int bid = blockIdx.x;
  const int nb  = (bid & 7) * (nwg >> 3) + (bid >> 3);   // XCD-bijective (nwg%8==0)
  const int brow = nb / nbn, bcol = nb % nbn;
  const int t = threadIdx.x, lane = t & 63, w = t >> 6;
  const int wm = w >> 2, wn = w & 3;
  const int l15 = lane & 15, lhi = lane >> 4;

  // ---- staging: thread t covers (lr = t>>2, slot cs = t&3) of a region, both kk
  const int lr = t >> 2, cs = t & 3;
  const int csw = cs ^ ((lr >> 1) & 3);                  // data chunk held in slot cs
  const int gA0 = (lr & 63) | ((lr & 64) << 1);          // inverse row perms
  const int gA1 = gA0 | 64;
  const int gB0 = (lr & 31) | ((lr & 0x60) << 1);
  const int gB1 = gB0 | 32;
  // u32 BYTE offsets from the matrix bases (saddr form)
  const uint vA0 = ((uint)(brow * 256 + gA0) * KD + (uint)csw * 8) * 2u;
  const uint vA1 = ((uint)(brow * 256 + gA1) * KD + (uint)csw * 8) * 2u;
  const uint vB0 = ((uint)(bcol * 256 + gB0) * KD + (uint)csw * 8) * 2u;
  const uint vB1 = ((uint)(bcol * 256 + gB1) * KD + (uint)csw * 8) * 2u;
  const char* Ab8 = (const char*)Ab;
  const char* Bb8 = (const char*)Bb;
  const int dstT = t * 8;                                // lr*32 + cs*8 (ushort idx)

// stage one 16KB region (2 GLL: kk0, kk1 = +64B global) at k-offset KO (elements)
#define STG(PB, OPOFF, SRC8, VOFF, R, KO) do { \
    GLL((SRC8) + (VOFF) + (KO) * 2,      &lds[(PB) + (OPOFF) + (R) * 4096 + dstT]); \
    GLL((SRC8) + (VOFF) + (KO) * 2 + 64, &lds[(PB) + (OPOFF) + 8192 + (R) * 4096 + dstT]); } while (0)

  // ---- fragment read bases (swizzled)
  const int swp = (lhi ^ ((l15 >> 1) & 3)) * 8;
  const ushort* fA  = &lds[(wm * 64 + l15) * 32 + swp];           // + PB + kk*8192 + (mf>>2)*4096 + (mf&3)*512
  const ushort* fB  = &lds[16384 + (wn * 32 + l15) * 32 + swp];   // + PB + kk*8192 + (nf>>1)*4096 + (nf&1)*512

#define RD_A4(DST, PB, HOFF, KK) \
    _Pragma("unroll") for (int m = 0; m < 4; ++m) \
      DST[m][KK] = *(const bf16x8*)&fA[(PB) + (KK) * 8192 + (HOFF) + m * 512];
#define RD_B4(DST, PB, HOFF) \
    _Pragma("unroll") for (int n = 0; n < 2; ++n) \
    _Pragma("unroll") for (int kk = 0; kk < 2; ++kk) \
      DST[n][kk] = *(const bf16x8*)&fB[(PB) + kk * 8192 + (HOFF) + n * 512];
// kk-outer so kk0 MFMAs issue first (same-phase kk1 reads complete meanwhile)
#define MM4(AR, BV, M0, N0) \
    _Pragma("unroll") for (int kk = 0; kk < 2; ++kk) \
    _Pragma("unroll") for (int m = 0; m < 4; ++m) \
    _Pragma("unroll") for (int n = 0; n < 2; ++n) \
      acc[(M0) + m][(N0) + n] = MFMA_(AR[m][kk], BV[n][kk], acc[(M0) + m][(N0) + n]);
#define BAR   __builtin_amdgcn_s_barrier()
#define PRIO1 __builtin_amdgcn_s_setprio(1)
#define PRIO0 __builtin_amdgcn_s_setprio(0)

  f32x4 acc[8][4] = {};
  bf16x8 a03[4][2], a47[4][2], b23[2][2], b01a[2][2], b01b[2][2];

// one K-tile: reads buf P, prefetches next-tile operands from buf Q in ph4,
// stages tile at k-offset KO into P's regions as they free.
#define KTILE(P, Q, KO, BU, BN) do { \
    RD_A4(a03, P, 0, 1) \
    RD_B4(b23, P, 4096) \
    PRIO1; MM4(a03, BU, 0, 0) PRIO0; BAR; \
    RD_A4(a47, P, 4096, 0) \
    STG(P, 16384, Bb8, vB0, 0, KO); \
    PRIO1; MM4(a03, b23, 0, 2) PRIO0; BAR; \
    RD_A4(a47, P, 4096, 1) \
    STG(P, 0, Ab8, vA0, 0, KO); \
    STG(P, 16384, Bb8, vB1, 1, KO); \
    PRIO1; MM4(a47, b23, 4, 2) PRIO0; \
    asm volatile("s_waitcnt vmcnt(6)" ::: "memory"); \
    BAR; \
    RD_A4(a03, Q, 0, 0) \
    RD_B4(BN, Q, 0) \
    STG(P, 0, Ab8, vA1, 1, KO); \
    PRIO1; MM4(a47, BU, 4, 0) PRIO0; BAR; \
  } while (0)

  // prologue: stage tile0 -> buf0, tile1 -> buf1 (8 GLL each)
  STG(0, 16384, Bb8, vB0, 0, 0);
  STG(0, 0, Ab8, vA0, 0, 0);
  STG(0, 16384, Bb8, vB1, 1, 0);
  STG(0, 0, Ab8, vA1, 1, 0);
  STG(32768, 16384, Bb8, vB0, 0, 64);
  STG(32768, 0, Ab8, vA0, 0, 64);
  STG(32768, 16384, Bb8, vB1, 1, 64);
  STG(32768, 0, Ab8, vA1, 1, 64);
  asm volatile("s_waitcnt vmcnt(8)" ::: "memory");
  BAR;
  // pre-read tile0's ph1 operands (A0 kk0 + B0)
  RD_A4(a03, 0, 0, 0)
  RD_B4(b01a, 0, 0)

#pragma unroll 1
  for (int i = 0; i < 8; ++i) {
    const int t2 = 2 * i + 2, t3 = 2 * i + 3;
    const int ko2 = (t2 < 16 ? t2 : 15) * 64;   // tail: dead re-stage (uniform vmcnt)
    const int ko3 = (t3 < 16 ? t3 : 15) * 64;
    KTILE(0, 32768, ko2, b01a, b01b);
    KTILE(32768, 0, ko3, b01b, b01a);
  }

  asm volatile("s_waitcnt vmcnt(0)" ::: "memory");
  __syncthreads();

  // ---- epilogue ----
  const int rowb = wm * 128;
  if constexpr (MODE == 0) {
    // reuse LDS as [256][64] bf16 x3 (dec/u/gate), XOR-swizzled 8-ushort chunks.
    // Fast math: rcp-based sigmoid/tanh, __logf softplus. Accumulate per-4-row
    // affine runs (P,L) from the bf16-ROUNDED d,u (must match scanC's replay).
    ushort* ldsD = lds;
    ushort* ldsU = lds + 16384;
    ushort* ldsG = lds + 32768;
    const int chl = wn * 16 + l15;           // channel within block's 64
    const int chg = bcol * 64 + chl;         // global channel
    const float ab = frcp(1.f + __expf(-log_a[chg]));   // a_base inline
    float Prun[8], Lrun[8];
#pragma unroll
    for (int mf = 0; mf < 8; ++mf) {
      const int rl0 = rowb + mf * 16 + lhi * 4;
      float P = 1.f, L = 0.f;
#pragma unroll
      for (int r = 0; r < 4; ++r) {
        const float zd = acc[mf][0][r];
        const float zs = acc[mf][1][r];
        const float zi = acc[mf][2][r];
        const float zg = acc[mf][3][r];
        float sp = fmaxf(zd, 0.f) + __logf(1.f + __expf(-fabsf(zd)));
        sp = fmaxf(sp, 1e-4f);
        const float dv = __expf(-sp * ab);
        const float sv = frcp(1.f + __expf(-zs));
        float tt = __expf(-2.f * fabsf(zi));
        float tv = (1.f - tt) * frcp(1.f + tt);
        tv = (zi < 0.f) ? -tv : tv;
        const float gv = frcp(1.f + __expf(-zg));
        const ushort dbits = sbf(dv);
        const ushort ubits = sbf(sv * tv);
        const int row = rl0 + r;
        const int idx = row * 64 + ((((chl >> 3) ^ (row & 7)) << 3) | (chl & 7));
        ldsD[idx] = dbits;
        ldsU[idx] = ubits;
        ldsG[idx] = sbf(gv);
        const float dq = bf2f(dbits), uq = bf2f(ubits);
        P *= dq;
        L = fmaf(dq, L, uq);
      }
      Prun[mf] = P; Lrun[mf] = L;
    }
    // ---- fused scanA: chunk (32-row) summaries via ordered shfl_down over lhi
    const int bq = brow >> 4;                       // batch (256 rows never cross b)
    const int cbase = (brow & 15) * 8 + wm * 4;     // global chunk base within b
#pragma unroll
    for (int j = 0; j < 4; ++j) {
      float Pe = Prun[2 * j],     Le = Lrun[2 * j];       // rows 0-15 of chunk
      float Po = Prun[2 * j + 1], Lo = Lrun[2 * j + 1];   // rows 16-31
      {
        float Pn = __shfl_down(Pe, 16), Ln = __shfl_down(Le, 16);
        Pe = Pe * Pn; Le = fmaf(Pn, Le, Ln);
        float Pm = __shfl_down(Po, 16), Lm = __shfl_down(Lo, 16);
        Po = Po * Pm; Lo = fmaf(Pm, Lo, Lm);
      }
      {
        float Pn = __shfl_down(Pe, 32), Ln = __shfl_down(Le, 32);
        Pe = Pe * Pn; Le = fmaf(Pn, Le, Ln);
        float Pm = __shfl_down(Po, 32), Lm = __shfl_down(Lo, 32);
        Po = Po * Pm; Lo = fmaf(Pm, Lo, Lm);
      }
      if (lhi == 0) {
        const float Pc = Pe * Po;
        const float Lc = fmaf(Po, Le, Lo);
        const size_t o = ((size_t)(bq * NCHUNK + cbase + j)) * D_ + chg;
        cP[o] = Pc; cL[o] = Lc;
      }
    }
    __syncthreads();
    const int srow = t >> 3, cD = t & 7;
    const size_t gbase = (size_t)(brow * 256) * D_ + bcol * 64 + cD * 8;
#pragma unroll
    for (int itp = 0; itp < 4; ++itp) {
      const int row = itp * 64 + srow;
      const int lidx = row * 64 + ((cD ^ (row & 7)) << 3);
      const size_t g = gbase + (size_t)row * D_;
      *(ushort8v*)&dec[g] = *(const ushort8v*)&ldsD[lidx];
      *(ushort8v*)&uu[g]  = *(const ushort8v*)&ldsU[lidx];
      *(ushort8v*)&gat[g] = *(const ushort8v*)&ldsG[lidx];
    }
  } else {
    const int colb = bcol * 256 + wn * 64;
#pragma unroll
    for (int mf = 0; mf < 8; ++mf) {
      const int rl0 = brow * 256 + rowb + mf * 16 + lhi * 4;
#pragma unroll
      for (int nf = 0; nf < 4; ++nf) {
        const int gc = colb + nf * 16 + l15;
#pragma unroll
        for (int r = 0; r < 4; ++r)
          outf[(size_t)(rl0 + r) * 1024 + gc] = acc[mf][nf][r];
      }
    }
  }
#undef KTILE
#undef STG
#undef RD_A4
#undef RD_B4
#undef MM4
}

// ---------------- scanC with fused prefix (scanB folded in) ----------------
// Each (b,c) block recomputes its own carry by composing chunk summaries 0..c-1
// (cP/cL are 4MB, L2-resident; <=127 fma-chain iters, fully parallel across blocks),
// then replays the chunk with gate fused, writing bf16 outb.
__global__ __launch_bounds__(512) void k_scanC(
    const ushort* __restrict__ dec, const ushort* __restrict__ uu,
    const ushort* __restrict__ gat,
    const float* __restrict__ cP, const float* __restrict__ cL,
    ushort* __restrict__ outb)
{
  const int t  = threadIdx.x;
  const int c  = blockIdx.x & (NCHUNK - 1);
  const int b  = blockIdx.x >> 7;
  const int e2 = t * 2;
  // prefix carry over chunks 0..c-1
  float s0 = 0.f, s1 = 0.f;
  {
    size_t pb = (size_t)b * NCHUNK * D_ + e2;
    for (int j = 0; j < c; ++j) {
      const size_t o = pb + (size_t)j * D_;
      const float2 p = *(const float2*)&cP[o];
      const float2 l = *(const float2*)&cL[o];
      s0 = fmaf(p.x, s0, l.x);
      s1 = fmaf(p.y, s1, l.y);
    }
  }
  size_t base = ((size_t)b * S_ + (size_t)c * CHLEN) * D_ + e2;
  for (int i = 0; i < CHLEN; ++i) {
    const uint dv = *(const uint*)(dec + base);
    const uint uv = *(const uint*)(uu + base);
    const uint gv = *(const uint*)(gat + base);
    s0 = fmaf(bf2f(dv & 0xffffu), s0, bf2f(uv & 0xffffu));
    s1 = fmaf(bf2f(dv >> 16),     s1, bf2f(uv >> 16));
    float o0 = bf2f(gv & 0xffffu) * s0;
    float o1 = bf2f(gv >> 16)     * s1;
    *(uint*)(outb + base) = pk2bf(o0, o1);
    base += D_;
  }
}

// ---------------- launcher ----------------
extern "C" void kernel_launch(void* const* d_in, const int* in_sizes, int n_in,
                              void* d_out, int out_size, void* d_ws, size_t ws_size,
                              hipStream_t stream) {
  const float* x     = (const float*)d_in[0];
  const float* W_in  = (const float*)d_in[1];
  const float* W_sel = (const float*)d_in[2];
  const float* W_gat = (const float*)d_in[3];
  const float* W_out = (const float*)d_in[4];
  const float* W_del = (const float*)d_in[5];
  const float* log_a = (const float*)d_in[6];
  float* y = (float*)d_out;

  char* ws = (char*)d_ws;
  size_t off = 0;
  auto alloc = [&](size_t bytes) { char* p = ws + off; off += (bytes + 255) & ~(size_t)255; return p; };
  ushort* xbf   = (ushort*)alloc((size_t)M_ * D_ * 2);   // reused as outb after GEMM0
  ushort* wcat  = (ushort*)alloc((size_t)NCAT * D_ * 2);
  ushort* woutb = (ushort*)alloc((size_t)D_ * D_ * 2);
  ushort* dec   = (ushort*)alloc((size_t)M_ * D_ * 2);
  ushort* uu    = (ushort*)alloc((size_t)M_ * D_ * 2);
  ushort* gat   = (ushort*)alloc((size_t)M_ * D_ * 2);
  float*  cP    = (float*)alloc((size_t)B_ * NCHUNK * D_ * 4);
  float*  cL    = (float*)alloc((size_t)B_ * NCHUNK * D_ * 4);
  ushort* outb  = xbf;

  // K0: all conversions in one kernel
  const int nq = NQ_X + NQ_W + NQ_O;
  k_prep<<<(nq + 255) / 256, 256, 0, stream>>>(
      x, W_del, W_sel, W_in, W_gat, W_out, xbf, wcat, woutb);

  // K1: fused 4-projection GEMM + activation epilogue + chunk summaries (scanA)
  gemm10<0><<<(M_ / 256) * (NCAT / 256), 512, 0, stream>>>(
      xbf, wcat, NCAT / 256, nullptr, dec, uu, gat, log_a, cP, cL);

  // K2: scan combine+replay (scanB fused into scanC)
  k_scanC<<<B_ * NCHUNK, 512, 0, stream>>>(dec, uu, gat, cP, cL, outb);

  // K3: output GEMM -> fp32 y
  gemm10<1><<<(M_ / 256) * (D_ / 256), 512, 0, stream>>>(
      outb, woutb, D_ / 256, y, nullptr, nullptr, nullptr, nullptr, nullptr, nullptr);
}

// Round 16
// 252.778 us; speedup vs baseline: 1.0693x; 1.0693x over previous
//
#include <hip/hip_runtime.h>
#include <hip/hip_bf16.h>
#include <math.h>

#define B_   4
#define S_   4096
#define D_   1024
#define M_   (B_*S_)        // 16384 rows
#define NCAT (4*D_)         // 4096 concat projection cols
#define KD   1024

#define NCHUNK 128          // scan chunks along S
#define CHLEN  (S_/NCHUNK)  // 32

typedef __bf16 bf16x8 __attribute__((ext_vector_type(8)));
typedef float  f32x4  __attribute__((ext_vector_type(4)));
typedef ushort ushort8v __attribute__((ext_vector_type(8)));

__device__ __forceinline__ ushort sbf(float f) {           // f32 -> bf16 (RNE, hw cvt)
  return __builtin_bit_cast(ushort, (__bf16)f);
}
__device__ __forceinline__ uint pk2bf(float lo, float hi) {
  return (uint)sbf(lo) | ((uint)sbf(hi) << 16);
}
__device__ __forceinline__ float bf2f(uint bits16) {
  union { uint u; float f; } v; v.u = bits16 << 16;
  return v.f;
}
__device__ __forceinline__ float frcp(float x) { return __builtin_amdgcn_rcpf(x); }

// global -> LDS direct (16B per lane). LDS dest linear: wave-uniform base + lane*16.
#define GLL(g, l) __builtin_amdgcn_global_load_lds( \
  (const __attribute__((address_space(1))) uint32_t*)(uintptr_t)(g), \
  (__attribute__((address_space(3))) uint32_t*)(uint32_t)(uintptr_t)(l), 16, 0, 0)

#define MFMA_(a, b, c) __builtin_amdgcn_mfma_f32_16x16x32_bf16(a, b, c, 0, 0, 0)

// ---------------- K0: all dtype conversions in one kernel ----------------
#define NQ_X  (M_*D_/4)
#define NQ_W  (NCAT*D_/4)
#define NQ_O  (D_*D_/4)
__global__ void k_prep(const float* __restrict__ x,
                       const float* __restrict__ wdel, const float* __restrict__ wsel,
                       const float* __restrict__ win,  const float* __restrict__ wgat,
                       const float* __restrict__ wout,
                       ushort* __restrict__ xbf, ushort* __restrict__ wcat,
                       ushort* __restrict__ woutb) {
  int i = blockIdx.x * blockDim.x + threadIdx.x;
  const float* src;
  ushort* dst;
  size_t so, eo;
  if (i < NQ_X) {
    src = x; dst = xbf; so = (size_t)i * 4; eo = so;
  } else if (i < NQ_X + NQ_W) {
    const int q = i - NQ_X;
    const int E = q * 4;
    const int n = E >> 10, col = E & 1023;
    const int p = (n >> 4) & 3;
    const int e = ((n >> 6) << 4) + (n & 15);
    src = (p == 0) ? wdel : (p == 1) ? wsel : (p == 2) ? win : wgat;
    dst = wcat; so = (size_t)e * 1024 + col; eo = E;
  } else if (i < NQ_X + NQ_W + NQ_O) {
    const int q = i - NQ_X - NQ_W;
    src = wout; dst = woutb; so = (size_t)q * 4; eo = so;
  } else return;
  const float4 v = *(const float4*)&src[so];
  uint2 o;
  o.x = pk2bf(v.x, v.y);
  o.y = pk2bf(v.z, v.w);
  *(uint2*)&dst[eo] = o;
}

// -------- 256x256 GEMM, K-tile 64, ONE barrier/phase, ds_read prefetched 1 phase ----
// (R9/R14 structure verbatim -- best passing variant.)  C[m][n] = sum_k A[m][k]*B[n][k].
//   buf PB in {0, 32768} ushorts; A region at PB+0, B at PB+16384;
//   idx = kk*8192 + R*4096 + lr*32 + s*8; swizzle s = c ^ ((r>>1)&3) (0-conflict).
// MODE 0 fuses: activation epilogue (fast math), scanA chunk summaries (shfl compose),
// a_base = sigmoid(log_a) inline.
template<int MODE>
__global__ __launch_bounds__(512, 2) void gemm10(
    const ushort* __restrict__ Ab, const ushort* __restrict__ Bb, int nbn,
    float* __restrict__ outf,
    ushort* __restrict__ dec, ushort* __restrict__ uu, ushort* __restrict__ gat,
    const float* __restrict__ log_a,
    float* __restrict__ cP, float* __restrict__ cL)
{
  __shared__ ushort lds[65536];  // 128 KB: 2 bufs x (A 32KB + B 32KB)

  const int nwg = gridDim.x;
  const int bid = blockIdx.x;
  const int nb  = (bid & 7) * (nwg >> 3) + (bid >> 3);   // XCD-bijective (nwg%8==0)
  const int brow = nb / nbn, bcol = nb % nbn;
  const int t = threadIdx.x, lane = t & 63, w = t >> 6;
  const int wm = w >> 2, wn = w & 3;
  const int l15 = lane & 15, lhi = lane >> 4;

  // ---- staging: thread t covers (lr = t>>2, slot cs = t&3) of a region, both kk
  const int lr = t >> 2, cs = t & 3;
  const int csw = cs ^ ((lr >> 1) & 3);                  // data chunk held in slot cs
  const int gA0 = (lr & 63) | ((lr & 64) << 1);          // inverse row perms
  const int gA1 = gA0 | 64;
  const int gB0 = (lr & 31) | ((lr & 0x60) << 1);
  const int gB1 = gB0 | 32;
  // u32 BYTE offsets from the matrix bases (saddr form)
  const uint vA0 = ((uint)(brow * 256 + gA0) * KD + (uint)csw * 8) * 2u;
  const uint vA1 = ((uint)(brow * 256 + gA1) * KD + (uint)csw * 8) * 2u;
  const uint vB0 = ((uint)(bcol * 256 + gB0) * KD + (uint)csw * 8) * 2u;
  const uint vB1 = ((uint)(bcol * 256 + gB1) * KD + (uint)csw * 8) * 2u;
  const char* Ab8 = (const char*)Ab;
  const char* Bb8 = (const char*)Bb;
  const int dstT = t * 8;                                // lr*32 + cs*8 (ushort idx)

// stage one 16KB region (2 GLL: kk0, kk1 = +64B global) at k-offset KO (elements)
#define STG(PB, OPOFF, SRC8, VOFF, R, KO) do { \
    GLL((SRC8) + (VOFF) + (KO) * 2,      &lds[(PB) + (OPOFF) + (R) * 4096 + dstT]); \
    GLL((SRC8) + (VOFF) + (KO) * 2 + 64, &lds[(PB) + (OPOFF) + 8192 + (R) * 4096 + dstT]); } while (0)

  // ---- fragment read bases (swizzled)
  const int swp = (lhi ^ ((l15 >> 1) & 3)) * 8;
  const ushort* fA  = &lds[(wm * 64 + l15) * 32 + swp];           // + PB + kk*8192 + (mf>>2)*4096 + (mf&3)*512
  const ushort* fB  = &lds[16384 + (wn * 32 + l15) * 32 + swp];   // + PB + kk*8192 + (nf>>1)*4096 + (nf&1)*512

#define RD_A4(DST, PB, HOFF, KK) \
    _Pragma("unroll") for (int m = 0; m < 4; ++m) \
      DST[m][KK] = *(const bf16x8*)&fA[(PB) + (KK) * 8192 + (HOFF) + m * 512];
#define RD_B4(DST, PB, HOFF) \
    _Pragma("unroll") for (int n = 0; n < 2; ++n) \
    _Pragma("unroll") for (int kk = 0; kk < 2; ++kk) \
      DST[n][kk] = *(const bf16x8*)&fB[(PB) + kk * 8192 + (HOFF) + n * 512];
// kk-outer so kk0 MFMAs issue first (same-phase kk1 reads complete meanwhile)
#define MM4(AR, BV, M0, N0) \
    _Pragma("unroll") for (int kk = 0; kk < 2; ++kk) \
    _Pragma("unroll") for (int m = 0; m < 4; ++m) \
    _Pragma("unroll") for (int n = 0; n < 2; ++n) \
      acc[(M0) + m][(N0) + n] = MFMA_(AR[m][kk], BV[n][kk], acc[(M0) + m][(N0) + n]);
#define BAR   __builtin_amdgcn_s_barrier()
#define PRIO1 __builtin_amdgcn_s_setprio(1)
#define PRIO0 __builtin_amdgcn_s_setprio(0)

  f32x4 acc[8][4] = {};
  bf16x8 a03[4][2], a47[4][2], b23[2][2], b01a[2][2], b01b[2][2];

// one K-tile: reads buf P, prefetches next-tile operands from buf Q in ph4,
// stages tile at k-offset KO into P's regions as they free.
#define KTILE(P, Q, KO, BU, BN) do { \
    RD_A4(a03, P, 0, 1) \
    RD_B4(b23, P, 4096) \
    PRIO1; MM4(a03, BU, 0, 0) PRIO0; BAR; \
    RD_A4(a47, P, 4096, 0) \
    STG(P, 16384, Bb8, vB0, 0, KO); \
    PRIO1; MM4(a03, b23, 0, 2) PRIO0; BAR; \
    RD_A4(a47, P, 4096, 1) \
    STG(P, 0, Ab8, vA0, 0, KO); \
    STG(P, 16384, Bb8, vB1, 1, KO); \
    PRIO1; MM4(a47, b23, 4, 2) PRIO0; \
    asm volatile("s_waitcnt vmcnt(6)" ::: "memory"); \
    BAR; \
    RD_A4(a03, Q, 0, 0) \
    RD_B4(BN, Q, 0) \
    STG(P, 0, Ab8, vA1, 1, KO); \
    PRIO1; MM4(a47, BU, 4, 0) PRIO0; BAR; \
  } while (0)

  // prologue: stage tile0 -> buf0, tile1 -> buf1 (8 GLL each)
  STG(0, 16384, Bb8, vB0, 0, 0);
  STG(0, 0, Ab8, vA0, 0, 0);
  STG(0, 16384, Bb8, vB1, 1, 0);
  STG(0, 0, Ab8, vA1, 1, 0);
  STG(32768, 16384, Bb8, vB0, 0, 64);
  STG(32768, 0, Ab8, vA0, 0, 64);
  STG(32768, 16384, Bb8, vB1, 1, 64);
  STG(32768, 0, Ab8, vA1, 1, 64);
  asm volatile("s_waitcnt vmcnt(8)" ::: "memory");
  BAR;
  // pre-read tile0's ph1 operands (A0 kk0 + B0)
  RD_A4(a03, 0, 0, 0)
  RD_B4(b01a, 0, 0)

#pragma unroll 1
  for (int i = 0; i < 8; ++i) {
    const int t2 = 2 * i + 2, t3 = 2 * i + 3;
    const int ko2 = (t2 < 16 ? t2 : 15) * 64;   // tail: dead re-stage (uniform vmcnt)
    const int ko3 = (t3 < 16 ? t3 : 15) * 64;
    KTILE(0, 32768, ko2, b01a, b01b);
    KTILE(32768, 0, ko3, b01b, b01a);
  }

  asm volatile("s_waitcnt vmcnt(0)" ::: "memory");
  __syncthreads();

  // ---- epilogue ----
  const int rowb = wm * 128;
  if constexpr (MODE == 0) {
    // reuse LDS as [256][64] bf16 x3 (dec/u/gate), XOR-swizzled 8-ushort chunks.
    // Fast math: rcp-based sigmoid/tanh, __logf softplus. Accumulate per-4-row
    // affine runs (P,L) from the bf16-ROUNDED d,u (must match scanC's replay).
    ushort* ldsD = lds;
    ushort* ldsU = lds + 16384;
    ushort* ldsG = lds + 32768;
    const int chl = wn * 16 + l15;           // channel within block's 64
    const int chg = bcol * 64 + chl;         // global channel
    const float ab = frcp(1.f + __expf(-log_a[chg]));   // a_base inline
    float Prun[8], Lrun[8];
#pragma unroll
    for (int mf = 0; mf < 8; ++mf) {
      const int rl0 = rowb + mf * 16 + lhi * 4;
      float P = 1.f, L = 0.f;
#pragma unroll
      for (int r = 0; r < 4; ++r) {
        const float zd = acc[mf][0][r];
        const float zs = acc[mf][1][r];
        const float zi = acc[mf][2][r];
        const float zg = acc[mf][3][r];
        float sp = fmaxf(zd, 0.f) + __logf(1.f + __expf(-fabsf(zd)));
        sp = fmaxf(sp, 1e-4f);
        const float dv = __expf(-sp * ab);
        const float sv = frcp(1.f + __expf(-zs));
        float tt = __expf(-2.f * fabsf(zi));
        float tv = (1.f - tt) * frcp(1.f + tt);
        tv = (zi < 0.f) ? -tv : tv;
        const float gv = frcp(1.f + __expf(-zg));
        const ushort dbits = sbf(dv);
        const ushort ubits = sbf(sv * tv);
        const int row = rl0 + r;
        const int idx = row * 64 + ((((chl >> 3) ^ (row & 7)) << 3) | (chl & 7));
        ldsD[idx] = dbits;
        ldsU[idx] = ubits;
        ldsG[idx] = sbf(gv);
        const float dq = bf2f(dbits), uq = bf2f(ubits);
        P *= dq;
        L = fmaf(dq, L, uq);
      }
      Prun[mf] = P; Lrun[mf] = L;
    }
    // ---- fused scanA: chunk (32-row) summaries via ordered shfl_down over lhi
    const int bq = brow >> 4;                       // batch (256 rows never cross b)
    const int cbase = (brow & 15) * 8 + wm * 4;     // global chunk base within b
#pragma unroll
    for (int j = 0; j < 4; ++j) {
      float Pe = Prun[2 * j],     Le = Lrun[2 * j];       // rows 0-15 of chunk
      float Po = Prun[2 * j + 1], Lo = Lrun[2 * j + 1];   // rows 16-31
      {
        float Pn = __shfl_down(Pe, 16), Ln = __shfl_down(Le, 16);
        Pe = Pe * Pn; Le = fmaf(Pn, Le, Ln);
        float Pm = __shfl_down(Po, 16), Lm = __shfl_down(Lo, 16);
        Po = Po * Pm; Lo = fmaf(Pm, Lo, Lm);
      }
      {
        float Pn = __shfl_down(Pe, 32), Ln = __shfl_down(Le, 32);
        Pe = Pe * Pn; Le = fmaf(Pn, Le, Ln);
        float Pm = __shfl_down(Po, 32), Lm = __shfl_down(Lo, 32);
        Po = Po * Pm; Lo = fmaf(Pm, Lo, Lm);
      }
      if (lhi == 0) {
        const float Pc = Pe * Po;
        const float Lc = fmaf(Po, Le, Lo);
        const size_t o = ((size_t)(bq * NCHUNK + cbase + j)) * D_ + chg;
        cP[o] = Pc; cL[o] = Lc;
      }
    }
    __syncthreads();
    const int srow = t >> 3, cD = t & 7;
    const size_t gbase = (size_t)(brow * 256) * D_ + bcol * 64 + cD * 8;
#pragma unroll
    for (int itp = 0; itp < 4; ++itp) {
      const int row = itp * 64 + srow;
      const int lidx = row * 64 + ((cD ^ (row & 7)) << 3);
      const size_t g = gbase + (size_t)row * D_;
      *(ushort8v*)&dec[g] = *(const ushort8v*)&ldsD[lidx];
      *(ushort8v*)&uu[g]  = *(const ushort8v*)&ldsU[lidx];
      *(ushort8v*)&gat[g] = *(const ushort8v*)&ldsG[lidx];
    }
  } else {
    const int colb = bcol * 256 + wn * 64;
#pragma unroll
    for (int mf = 0; mf < 8; ++mf) {
      const int rl0 = brow * 256 + rowb + mf * 16 + lhi * 4;
#pragma unroll
      for (int nf = 0; nf < 4; ++nf) {
        const int gc = colb + nf * 16 + l15;
#pragma unroll
        for (int r = 0; r < 4; ++r)
          outf[(size_t)(rl0 + r) * 1024 + gc] = acc[mf][nf][r];
      }
    }
  }
#undef KTILE
#undef STG
#undef RD_A4
#undef RD_B4
#undef MM4
}

// ---------------- scan phases B, C (separate: O(N) summary pass, then replay) ----
__global__ __launch_bounds__(64) void k_scanB(
    const float* __restrict__ cP, const float* __restrict__ cL, float* __restrict__ carry)
{
  const int idx = blockIdx.x * 64 + threadIdx.x;  // 0..B_*D_-1
  const int b = idx >> 10, e = idx & 1023;
  float st = 0.f;
  size_t base = (size_t)b * NCHUNK * D_ + e;
  for (int c = 0; c < NCHUNK; ++c) {
    size_t o = base + (size_t)c * D_;
    carry[o] = st;
    st = fmaf(cP[o], st, cL[o]);
  }
}

__global__ __launch_bounds__(512) void k_scanC(
    const ushort* __restrict__ dec, const ushort* __restrict__ uu,
    const ushort* __restrict__ gat, const float* __restrict__ carry,
    ushort* __restrict__ outb)
{
  const int t  = threadIdx.x;
  const int c  = blockIdx.x & (NCHUNK - 1);
  const int b  = blockIdx.x >> 7;
  const int e2 = t * 2;
  size_t co = ((size_t)b * NCHUNK + c) * D_ + e2;
  float s0 = carry[co], s1 = carry[co + 1];
  size_t base = ((size_t)b * S_ + (size_t)c * CHLEN) * D_ + e2;
  for (int i = 0; i < CHLEN; ++i) {
    const uint dv = *(const uint*)(dec + base);
    const uint uv = *(const uint*)(uu + base);
    const uint gv = *(const uint*)(gat + base);
    s0 = fmaf(bf2f(dv & 0xffffu), s0, bf2f(uv & 0xffffu));
    s1 = fmaf(bf2f(dv >> 16),     s1, bf2f(uv >> 16));
    float o0 = bf2f(gv & 0xffffu) * s0;
    float o1 = bf2f(gv >> 16)     * s1;
    *(uint*)(outb + base) = pk2bf(o0, o1);
    base += D_;
  }
}

// ---------------- launcher ----------------
extern "C" void kernel_launch(void* const* d_in, const int* in_sizes, int n_in,
                              void* d_out, int out_size, void* d_ws, size_t ws_size,
                              hipStream_t stream) {
  const float* x     = (const float*)d_in[0];
  const float* W_in  = (const float*)d_in[1];
  const float* W_sel = (const float*)d_in[2];
  const float* W_gat = (const float*)d_in[3];
  const float* W_out = (const float*)d_in[4];
  const float* W_del = (const float*)d_in[5];
  const float* log_a = (const float*)d_in[6];
  float* y = (float*)d_out;

  char* ws = (char*)d_ws;
  size_t off = 0;
  auto alloc = [&](size_t bytes) { char* p = ws + off; off += (bytes + 255) & ~(size_t)255; return p; };
  ushort* xbf   = (ushort*)alloc((size_t)M_ * D_ * 2);   // reused as outb after GEMM0
  ushort* wcat  = (ushort*)alloc((size_t)NCAT * D_ * 2);
  ushort* woutb = (ushort*)alloc((size_t)D_ * D_ * 2);
  ushort* dec   = (ushort*)alloc((size_t)M_ * D_ * 2);
  ushort* uu    = (ushort*)alloc((size_t)M_ * D_ * 2);
  ushort* gat   = (ushort*)alloc((size_t)M_ * D_ * 2);
  float*  cP    = (float*)alloc((size_t)B_ * NCHUNK * D_ * 4);
  float*  cL    = (float*)alloc((size_t)B_ * NCHUNK * D_ * 4);
  float*  carry = (float*)alloc((size_t)B_ * NCHUNK * D_ * 4);
  ushort* outb  = xbf;

  // K0: all conversions in one kernel
  const int nq = NQ_X + NQ_W + NQ_O;
  k_prep<<<(nq + 255) / 256, 256, 0, stream>>>(
      x, W_del, W_sel, W_in, W_gat, W_out, xbf, wcat, woutb);

  // K1: fused 4-projection GEMM + activation epilogue + chunk summaries (scanA)
  gemm10<0><<<(M_ / 256) * (NCAT / 256), 512, 0, stream>>>(
      xbf, wcat, NCAT / 256, nullptr, dec, uu, gat, log_a, cP, cL);

  // K2: scan combine (one pass over L2-resident summaries), then replay
  k_scanB<<<(B_ * D_) / 64, 64, 0, stream>>>(cP, cL, carry);
  k_scanC<<<B_ * NCHUNK, 512, 0, stream>>>(dec, uu, gat, carry, outb);

  // K3: output GEMM -> fp32 y
  gemm10<1><<<(M_ / 256) * (D_ / 256), 512, 0, stream>>>(
      outb, woutb, D_ / 256, y, nullptr, nullptr, nullptr, nullptr, nullptr, nullptr);
}